// Round 5
// baseline (917.976 us; speedup 1.0000x reference)
//
#include <hip/hip_runtime.h>
#include <math.h>

#define TT 32
#define MAXREC 8
#define NBLK 256
#define NTHR 512

// workspace byte offsets
#define OFF_ZBUF   0u          // 128*128 f32 = 65536 (z rows, linear)
#define OFF_KEYS   65536u      // 128*128 u64 = 131072 (server s x row r candidate keys)
#define OFF_CTR    196608u     // 512 u32 (barrier control)
#define OFF_OUTH   198656u     // 4096*128 f32 = 2097152
#define OFF_RST    2295808u    // 128*4 f32

// ctr dword indices (64B padding between hot words)
#define C_AGRP(g)  ((g)*16)        // owners arrival, 4 groups of 32
#define C_AMID     64
#define C_BGRP(g)  (80+(g)*16)     // servers arrival, 4 groups of 32
#define C_BMID     144
#define C_AREL(g)  (160+(g)*16)    // 4 release words, polled by server groups
#define C_BREL(g)  (224+(g)*16)    // 4 release words, polled by owner groups

#define SENT 0x7FFFFFFFu
#define LOGN 33554432u        // 128*32*8192
#define TWO_PI_F 6.283185307179586f

typedef float f32x4 __attribute__((ext_vector_type(4)));
typedef unsigned long long u64;

__device__ __forceinline__ float wredsum(float v) {
#pragma unroll
  for (int m = 32; m > 0; m >>= 1) v += __shfl_xor(v, m);
  return v;
}

__device__ __forceinline__ u64 shflx64(u64 v, int m) {
  int lo = __shfl_xor((int)(unsigned)(v & 0xffffffffull), m);
  int hi = __shfl_xor((int)(unsigned)(v >> 32), m);
  return ((u64)(unsigned)hi << 32) | (unsigned)lo;
}

// monotone float->u32, pack with idx: u64-min == (min dist, then min idx) == jnp.argmin tie-break
__device__ __forceinline__ u64 packkey(float d, unsigned c) {
  unsigned u = __float_as_uint(d);
  u = (u & 0x80000000u) ? ~u : (u | 0x80000000u);
  return ((u64)u << 32) | c;
}
__device__ __forceinline__ float unpackd2(u64 key) {
  unsigned hi = (unsigned)(key >> 32);
  unsigned orig = (hi & 0x80000000u) ? (hi & 0x7fffffffu) : ~hi;
  return __uint_as_float(orig);
}

// ---- coherent (cross-XCD, L2-bypass) accesses ----
__device__ __forceinline__ unsigned ld_coh32(const unsigned* p) {
  unsigned v;
  asm volatile("global_load_dword %0, %1, off sc0 sc1\n\ts_waitcnt vmcnt(0)"
               : "=&v"(v) : "v"(p) : "memory");
  return v;
}
__device__ __forceinline__ void st_coh_f32(float* p, float v) {
  asm volatile("global_store_dword %0, %1, off sc0 sc1" :: "v"(p), "v"(v) : "memory");
}
__device__ __forceinline__ void st_coh32(unsigned* p, unsigned v) {
  asm volatile("global_store_dword %0, %1, off sc0 sc1" :: "v"(p), "v"(v) : "memory");
}
__device__ __forceinline__ void st_coh64(u64* p, u64 v) {
  asm volatile("global_store_dwordx2 %0, %1, off sc0 sc1" :: "v"(p), "v"(v) : "memory");
}

__device__ __forceinline__ unsigned rmw_inc(unsigned* p) {
  return __hip_atomic_fetch_add(p, 1u, __ATOMIC_RELAXED, __HIP_MEMORY_SCOPE_AGENT);
}

__device__ __forceinline__ unsigned poll_ge(const unsigned* p, unsigned tgt) {
  unsigned v = ld_coh32(p);
  while ((int)(v - tgt) < 0) {
    __builtin_amdgcn_s_sleep(2);
    v = ld_coh32(p);
  }
  return v;
}

// 8 coherent 16B loads + wait (single round trip)
__device__ __forceinline__ void ld8w(const float* base,
    unsigned o0, unsigned o1, unsigned o2, unsigned o3,
    unsigned o4, unsigned o5, unsigned o6, unsigned o7,
    f32x4& a0, f32x4& a1, f32x4& a2, f32x4& a3,
    f32x4& a4, f32x4& a5, f32x4& a6, f32x4& a7) {
  asm volatile(
      "global_load_dwordx4 %0, %8, %16 sc0 sc1\n\t"
      "global_load_dwordx4 %1, %9, %16 sc0 sc1\n\t"
      "global_load_dwordx4 %2, %10, %16 sc0 sc1\n\t"
      "global_load_dwordx4 %3, %11, %16 sc0 sc1\n\t"
      "global_load_dwordx4 %4, %12, %16 sc0 sc1\n\t"
      "global_load_dwordx4 %5, %13, %16 sc0 sc1\n\t"
      "global_load_dwordx4 %6, %14, %16 sc0 sc1\n\t"
      "global_load_dwordx4 %7, %15, %16 sc0 sc1\n\t"
      "s_waitcnt vmcnt(0)"
      : "=&v"(a0), "=&v"(a1), "=&v"(a2), "=&v"(a3),
        "=&v"(a4), "=&v"(a5), "=&v"(a6), "=&v"(a7)
      : "v"(o0), "v"(o1), "v"(o2), "v"(o3),
        "v"(o4), "v"(o5), "v"(o6), "v"(o7),
        "s"(base)
      : "memory");
}
// 8 coherent 8B loads, no wait
__device__ __forceinline__ void ld8x2_issue(const char* base,
    unsigned o0, unsigned o1, unsigned o2, unsigned o3,
    unsigned o4, unsigned o5, unsigned o6, unsigned o7,
    u64& a0, u64& a1, u64& a2, u64& a3, u64& a4, u64& a5, u64& a6, u64& a7) {
  asm volatile(
      "global_load_dwordx2 %0, %8, %16 sc0 sc1\n\t"
      "global_load_dwordx2 %1, %9, %16 sc0 sc1\n\t"
      "global_load_dwordx2 %2, %10, %16 sc0 sc1\n\t"
      "global_load_dwordx2 %3, %11, %16 sc0 sc1\n\t"
      "global_load_dwordx2 %4, %12, %16 sc0 sc1\n\t"
      "global_load_dwordx2 %5, %13, %16 sc0 sc1\n\t"
      "global_load_dwordx2 %6, %14, %16 sc0 sc1\n\t"
      "global_load_dwordx2 %7, %15, %16 sc0 sc1"
      : "=&v"(a0), "=&v"(a1), "=&v"(a2), "=&v"(a3),
        "=&v"(a4), "=&v"(a5), "=&v"(a6), "=&v"(a7)
      : "v"(o0), "v"(o1), "v"(o2), "v"(o3),
        "v"(o4), "v"(o5), "v"(o6), "v"(o7),
        "s"(base)
      : "memory");
}
// 8 more 8B loads + wait for ALL 16
__device__ __forceinline__ void ld8x2_wait(const char* base,
    unsigned o0, unsigned o1, unsigned o2, unsigned o3,
    unsigned o4, unsigned o5, unsigned o6, unsigned o7,
    u64& a0, u64& a1, u64& a2, u64& a3, u64& a4, u64& a5, u64& a6, u64& a7,
    u64& t0, u64& t1, u64& t2, u64& t3, u64& t4, u64& t5, u64& t6, u64& t7) {
  asm volatile(
      "global_load_dwordx2 %0, %16, %24 sc0 sc1\n\t"
      "global_load_dwordx2 %1, %17, %24 sc0 sc1\n\t"
      "global_load_dwordx2 %2, %18, %24 sc0 sc1\n\t"
      "global_load_dwordx2 %3, %19, %24 sc0 sc1\n\t"
      "global_load_dwordx2 %4, %20, %24 sc0 sc1\n\t"
      "global_load_dwordx2 %5, %21, %24 sc0 sc1\n\t"
      "global_load_dwordx2 %6, %22, %24 sc0 sc1\n\t"
      "global_load_dwordx2 %7, %23, %24 sc0 sc1\n\t"
      "s_waitcnt vmcnt(0)"
      : "=&v"(a0), "=&v"(a1), "=&v"(a2), "=&v"(a3),
        "=&v"(a4), "=&v"(a5), "=&v"(a6), "=&v"(a7),
        "+v"(t0), "+v"(t1), "+v"(t2), "+v"(t3),
        "+v"(t4), "+v"(t5), "+v"(t6), "+v"(t7)
      : "v"(o0), "v"(o1), "v"(o2), "v"(o3),
        "v"(o4), "v"(o5), "v"(o6), "v"(o7),
        "s"(base)
      : "memory");
}

__global__ __launch_bounds__(512) void sacrsn_init(char* __restrict__ ws) {
  unsigned* ctr = (unsigned*)(ws + OFF_CTR);
  ctr[threadIdx.x] = 0u;
}

__global__ __launch_bounds__(NTHR) void sacrsn_main(
    const int* __restrict__ x_seq, const float* __restrict__ enc,
    const float* __restrict__ vqe,
    const float* __restrict__ nrg, const float* __restrict__ nrb,
    const float* __restrict__ nig, const float* __restrict__ nib,
    const float* __restrict__ qWr, const float* __restrict__ qbr,
    const float* __restrict__ qWi, const float* __restrict__ qbi,
    const float* __restrict__ gtw, const float* __restrict__ gtb,
    const float* __restrict__ aW, const float* __restrict__ ab,
    const float* __restrict__ hbp, const float* __restrict__ igp,
    float* __restrict__ dout, char* __restrict__ ws)
{
  float* zbuf = (float*)(ws + OFF_ZBUF);
  u64*   keys = (u64*)(ws + OFF_KEYS);
  unsigned* ctr = (unsigned*)(ws + OFF_CTR);
  float* outh = (float*)(ws + OFF_OUTH);
  float* rst  = (float*)(ws + OFF_RST);

  const int tid = threadIdx.x;
  const int wv = tid >> 6, ln = tid & 63;
  const int blk = blockIdx.x;
  const bool owner = (blk < 128);

  // ---- LDS ----
  __shared__ float els[64 * 128];         // server: 64 codes, swizzled (32 KB)
  __shared__ float zloc[128 * 128];       // server: all rows z, swizzled (64 KB)
  __shared__ u64 vtmp[128 * 17];          // server: per-row partial mins (17 KB, padded)
  __shared__ float esqL[64];
  __shared__ float z2locL[128];
  __shared__ float memLr[32 * 65];        // owner
  __shared__ float memLi[32 * 65];
  __shared__ float gwrowL[128], pangL[64], zfmL[128], zqL[128];
  __shared__ float qkL[6][64], simL[32], attnL[32], mrL[64], miL[64];
  __shared__ unsigned idxL[128] __attribute__((aligned(16)));
  __shared__ u64 key128L[128];
  __shared__ float arbWL[3 * 128];
  __shared__ float scalL[8], entpL[2], vqpL[2], wsumL[2];
  __shared__ float accL[4], totL[4];
  __shared__ float dmeanS;
  __shared__ u64 actMbuf[2][2], actN[2];
  __shared__ unsigned stopF;

  const float alpha = 1.0f / (1.0f + expf(-igp[0]));
  const float onema = 1.0f - alpha;
  const float hbias = log1pf(expf(hbp[0]));
  const float gtb0 = gtb[0];

  if (!owner) {
    // ================= VQ server: blocks 128..255, 64 codes each =================
    const int s = blk - 128;
#pragma unroll
    for (int j = 0; j < 4; ++j) {
      int f4 = tid + j * NTHR;           // 0..2047
      int c = f4 >> 5, k4 = f4 & 31;
      float4 v = *(const float4*)&vqe[((size_t)(s * 64 + c) << 7) + (k4 << 2)];
      *(float4*)&els[(c << 7) + ((k4 ^ (c & 31)) << 2)] = v;
    }
    __syncthreads();
    if (tid < 64) {
      float sm = 0.0f;
#pragma unroll 8
      for (int k4 = 0; k4 < 32; ++k4) {
        float4 v = *(const float4*)&els[(tid << 7) + ((k4 ^ (tid & 31)) << 2)];
        sm = fmaf(v.x, v.x, fmaf(v.y, v.y, fmaf(v.z, v.z, fmaf(v.w, v.w, sm))));
      }
      esqL[tid] = sm;
    }
    __syncthreads();
    unsigned k = 0;
    while (true) {
      if (tid == 0) {
        unsigned v = poll_ge(&ctr[C_AREL(s >> 5)], k + 1u);
        stopF = (v >= 0x7F000000u) ? 1u : 0u;
      }
      __syncthreads();
      if (stopF) break;
      // stage z: 8 coherent 16B loads per thread, single round trip
      {
        f32x4 a0, a1, a2, a3, a4, a5, a6, a7;
        const unsigned tb = (unsigned)tid * 16u;
        ld8w(zbuf, tb, tb + 8192u, tb + 16384u, tb + 24576u,
             tb + 32768u, tb + 40960u, tb + 49152u, tb + 57344u,
             a0, a1, a2, a3, a4, a5, a6, a7);
        __builtin_amdgcn_sched_barrier(0);
        f32x4 va[8] = {a0, a1, a2, a3, a4, a5, a6, a7};
#pragma unroll
        for (int u = 0; u < 8; ++u) {
          int f4 = u * NTHR + tid;
          int row = f4 >> 5, k4 = f4 & 31;
          *(f32x4*)&zloc[(row << 7) + ((k4 ^ (row & 31)) << 2)] = va[u];
        }
      }
      __syncthreads();
      // per-row z^2
      if (tid < 128) {
        float sm = 0.0f;
#pragma unroll 8
        for (int k4 = 0; k4 < 32; ++k4) {
          float4 q = *(const float4*)&zloc[(tid << 7) + ((k4 ^ (tid & 31)) << 2)];
          sm = fmaf(q.x, q.x, fmaf(q.y, q.y, fmaf(q.z, q.z, fmaf(q.w, q.w, sm))));
        }
        z2locL[tid] = sm;
      }
      // VQ: 64 codes x 128 rows, thread tile 4 rows x 4 codes
      const int rt = tid & 31, ct = tid >> 5;   // ct 0..15
      float acc[4][4];
#pragma unroll
      for (int rr = 0; rr < 4; ++rr)
#pragma unroll
        for (int cc = 0; cc < 4; ++cc) acc[rr][cc] = 0.0f;
#pragma unroll 2
      for (int k4 = 0; k4 < 32; ++k4) {
        float4 zv[4], ev[4];
#pragma unroll
        for (int rr = 0; rr < 4; ++rr)
          zv[rr] = *(const float4*)&zloc[((rt + rr * 32) << 7) + ((k4 ^ rt) << 2)];
#pragma unroll
        for (int cc = 0; cc < 4; ++cc) {
          int cl = ct * 4 + cc;
          ev[cc] = *(const float4*)&els[(cl << 7) + ((k4 ^ (cl & 31)) << 2)];
        }
#pragma unroll
        for (int rr = 0; rr < 4; ++rr)
#pragma unroll
          for (int cc = 0; cc < 4; ++cc)
            acc[rr][cc] = fmaf(zv[rr].x, ev[cc].x, fmaf(zv[rr].y, ev[cc].y,
                          fmaf(zv[rr].z, ev[cc].z, fmaf(zv[rr].w, ev[cc].w, acc[rr][cc]))));
      }
      __syncthreads();  // z2locL ready for all
#pragma unroll
      for (int rr = 0; rr < 4; ++rr) {
        const int row = rt + rr * 32;
        const float z2r = z2locL[row];
        u64 key = ~0ull;
#pragma unroll
        for (int cc = 0; cc < 4; ++cc) {
          int cl = ct * 4 + cc;
          float d2 = (z2r - 2.0f * acc[rr][cc]) + esqL[cl];
          u64 pk = packkey(d2, (unsigned)(s * 64 + cl));
          if (pk < key) key = pk;
        }
        vtmp[row * 17 + ct] = key;
      }
      __syncthreads();
      if (tid < 128) {
        u64 kmin = vtmp[tid * 17];
#pragma unroll
        for (int w = 1; w < 16; ++w) { u64 o = vtmp[tid * 17 + w]; if (o < kmin) kmin = o; }
        st_coh64(&keys[(size_t)s * 128 + tid], kmin);
      }
      __syncthreads();  // drain stores (per-wave vmcnt at barrier)
      if (tid == 0) {
        unsigned a = rmw_inc(&ctr[C_BGRP(s >> 5)]);
        if ((a & 31u) == 31u) {
          unsigned b = rmw_inc(&ctr[C_BMID]);
          if ((b & 3u) == 3u) {
#pragma unroll
            for (int g = 0; g < 4; ++g) st_coh32(&ctr[C_BREL(g)], k + 1u);
          }
        }
      }
      k++;
    }
    return;
  }

  // ================= owner: blocks 0..127, row = blk =================
  float lnG = 0.0f, lnB = 0.0f, gtwv = 0.0f;
  if (tid < 64) { lnG = nrg[tid]; lnB = nrb[tid]; }
  else if (tid < 128) { lnG = nig[tid - 64]; lnB = nib[tid - 64]; }
  if (tid < 128) gtwv = gtw[tid];
  for (int i = tid; i < 32 * 65; i += NTHR) { memLr[i] = 0.0f; memLi[i] = 0.0f; }
  if (tid < 128) gwrowL[tid] = 0.0f;
  if (tid < 4) { totL[tid] = 0.0f; accL[tid] = 0.0f; }
  for (int i = tid; i < 384; i += NTHR) arbWL[i] = aW[i];
  __syncthreads();

  unsigned k = 0;
  for (int t = 0; t < TT; ++t) {
    for (int it = 0; it < MAXREC; ++it) {
      const unsigned pc = k & 1u;
      // ---------- A: merge (it0) + LN own row -> zbuf ----------
      if (it == 0 && tid < 2) actMbuf[pc][tid] = ~0ull;
      float val = 0.0f;
      if (it == 0) {
        float pr = 0.0f, gr = 0.0f;
        if (tid < 128) {
          pr = gwrowL[tid];
          int tok = x_seq[blk * TT + t];
          gr = fmaf(alpha, pr, onema * enc[((size_t)tok << 7) + tid]);
        }
        if (t > 0 && tid < 128) {
          outh[((size_t)blk * TT + (t - 1)) * 128 + tid] = pr;
          float part = wredsum(pr * gtwv);
          if (ln == 0) wsumL[wv] = part;
        }
        if (tid < 4) { if (t > 0) totL[tid] += accL[tid]; accL[tid] = 0.0f; }
        if (tid >= 64 && tid < 128) zqL[tid - 64] = gr;  // gi exchange
        __syncthreads();
        if (t > 0 && tid < 128) {
          float wg = 1.0f / (1.0f + expf(-(wsumL[0] + wsumL[1] + gtb0)));
          int slot = 32 - t;
          float* m = (tid < 64) ? &memLr[slot * 65 + tid] : &memLi[slot * 65 + (tid - 64)];
          *m = fmaf(wg, pr, (1.0f - wg) * (*m));
        }
        if (tid < 64) pangL[tid] = atan2f(zqL[tid], gr);
        if (tid < 128) gwrowL[tid] = gr;
        val = gr;
      } else {
        val = (tid < 128) ? gwrowL[tid] : 0.0f;
      }
      if (tid < 128) {
        float mu = wredsum(val) * 0.015625f;
        float xc = val - mu;
        float vr = wredsum(xc * xc) * 0.015625f;
        float z = xc * (1.0f / sqrtf(vr + 1e-5f)) * lnG + lnB;
        zfmL[tid] = z;
        st_coh_f32(&zbuf[(blk << 7) + tid], z);
      }
      __syncthreads();  // drains z stores before arrival
      if (tid == 0) {   // A arrival (owners do NOT poll A)
        unsigned a = rmw_inc(&ctr[C_AGRP(blk >> 5)]);
        if ((a & 31u) == 31u) {
          unsigned b = rmw_inc(&ctr[C_AMID]);
          if ((b & 3u) == 3u) {
#pragma unroll
            for (int g = 0; g < 4; ++g) st_coh32(&ctr[C_AREL(g)], k + 1u);
          }
        }
      }
      // ---------- idx-free C work (overlaps server VQ) ----------
      if (tid < 192) {
        const int h = tid >> 6, j = tid & 63;
        const float* wr = qWr + h * 4096 + j * 64;
        const float* wi = qWi + h * 4096 + j * 64;
        float da = 0.0f, db_ = 0.0f, dc = 0.0f, de = 0.0f;
#pragma unroll 4
        for (int d4 = 0; d4 < 64; d4 += 4) {
          float4 wrv = *(const float4*)&wr[d4];
          float4 wiv = *(const float4*)&wi[d4];
          float4 crv = *(const float4*)&zfmL[d4];
          float4 civ = *(const float4*)&zfmL[64 + d4];
          da = fmaf(crv.x, wrv.x, fmaf(crv.y, wrv.y, fmaf(crv.z, wrv.z, fmaf(crv.w, wrv.w, da))));
          db_ = fmaf(civ.x, wiv.x, fmaf(civ.y, wiv.y, fmaf(civ.z, wiv.z, fmaf(civ.w, wiv.w, db_))));
          dc = fmaf(civ.x, wrv.x, fmaf(civ.y, wrv.y, fmaf(civ.z, wrv.z, fmaf(civ.w, wrv.w, dc))));
          de = fmaf(crv.x, wiv.x, fmaf(crv.y, wiv.y, fmaf(crv.z, wiv.z, fmaf(crv.w, wiv.w, de))));
        }
        float brv = qbr[h * 64 + j], biv = qbi[h * 64 + j];
        qkL[2 * h][j] = da + brv - db_ - biv;
        qkL[2 * h + 1][j] = dc + brv + de + biv;
      } else if (tid < 224) {
        const int s2 = tid - 192;
        float a2 = 0.0f;
        for (int d = 0; d < 64; ++d)
          a2 = fmaf(memLr[s2 * 65 + d], zfmL[d], fmaf(memLi[s2 * 65 + d], zfmL[64 + d], a2));
        simL[s2] = a2;
      } else if (tid < 227) {
        const int h = tid - 224;
        float a2 = ab[h];
        for (int k2 = 0; k2 < 128; ++k2) a2 = fmaf(zfmL[k2], arbWL[h * 128 + k2], a2);
        scalL[3 + h] = a2;  // pre-softmax arb logits
      }
      __syncthreads();
      if (tid < 64) {
        float p = fmaf(qkL[0][tid], qkL[2][tid], qkL[1][tid] * qkL[3][tid]);
        p = wredsum(p);
        if (tid == 0) scalL[0] = 1.0f / (1.0f + expf(-p));
      } else if (tid < 96) {
        const int s2 = tid - 64;
        float v = simL[s2];
        float m = v;
#pragma unroll
        for (int msk = 16; msk > 0; msk >>= 1) m = fmaxf(m, __shfl_xor(m, msk));
        float e = expf(v - m);
        float ss = e;
#pragma unroll
        for (int msk = 16; msk > 0; msk >>= 1) ss += __shfl_xor(ss, msk);
        attnL[s2] = e / ss;
      } else if (tid == 96) {
        float a0 = scalL[3], a1 = scalL[4], a2 = scalL[5];
        float m = fmaxf(a0, fmaxf(a1, a2));
        float e0 = expf(a0 - m), e1 = expf(a1 - m), e2 = expf(a2 - m);
        float ssum = e0 + e1 + e2;
        scalL[3] = e0 / ssum; scalL[4] = e1 / ssum; scalL[5] = e2 / ssum;
      }
      __syncthreads();
      if (tid < 128) {  // attention readout
        const int d = ln;
        const float* ml = (wv == 0) ? memLr : memLi;
        float a2 = 0.0f;
#pragma unroll 4
        for (int s2 = 0; s2 < 32; ++s2) a2 = fmaf(attnL[s2], ml[s2 * 65 + d], a2);
        if (wv == 0) mrL[d] = a2; else miL[d] = a2;
      }
      // ---------- wait for servers ----------
      if (tid == 0) poll_ge(&ctr[C_BREL(blk >> 5)], k + 1u);
      __syncthreads();
      // ---------- gather ALL keys, tournament min per row ----------
      {
        const int r = tid >> 2, sc = tid & 3;
        const char* kb = (const char*)keys;
        const unsigned bo = (unsigned)(sc * 32768 + r * 8);
        u64 a0, a1, a2, a3, a4, a5, a6, a7, b0, b1, b2, b3, b4, b5, b6, b7;
        ld8x2_issue(kb, bo, bo + 1024u, bo + 2048u, bo + 3072u,
                    bo + 4096u, bo + 5120u, bo + 6144u, bo + 7168u,
                    a0, a1, a2, a3, a4, a5, a6, a7);
        ld8x2_wait(kb, bo + 8192u, bo + 9216u, bo + 10240u, bo + 11264u,
                   bo + 12288u, bo + 13312u, bo + 14336u, bo + 15360u,
                   b0, b1, b2, b3, b4, b5, b6, b7,
                   a0, a1, a2, a3, a4, a5, a6, a7);
        u64 m = a0;
        if (a1 < m) m = a1; if (a2 < m) m = a2; if (a3 < m) m = a3;
        if (a4 < m) m = a4; if (a5 < m) m = a5; if (a6 < m) m = a6; if (a7 < m) m = a7;
        if (b0 < m) m = b0; if (b1 < m) m = b1; if (b2 < m) m = b2; if (b3 < m) m = b3;
        if (b4 < m) m = b4; if (b5 < m) m = b5; if (b6 < m) m = b6; if (b7 < m) m = b7;
        ld8x2_issue(kb, bo + 16384u, bo + 17408u, bo + 18432u, bo + 19456u,
                    bo + 20480u, bo + 21504u, bo + 22528u, bo + 23552u,
                    a0, a1, a2, a3, a4, a5, a6, a7);
        ld8x2_wait(kb, bo + 24576u, bo + 25600u, bo + 26624u, bo + 27648u,
                   bo + 28672u, bo + 29696u, bo + 30720u, bo + 31744u,
                   b0, b1, b2, b3, b4, b5, b6, b7,
                   a0, a1, a2, a3, a4, a5, a6, a7);
        if (a0 < m) m = a0; if (a1 < m) m = a1; if (a2 < m) m = a2; if (a3 < m) m = a3;
        if (a4 < m) m = a4; if (a5 < m) m = a5; if (a6 < m) m = a6; if (a7 < m) m = a7;
        if (b0 < m) m = b0; if (b1 < m) m = b1; if (b2 < m) m = b2; if (b3 < m) m = b3;
        if (b4 < m) m = b4; if (b5 < m) m = b5; if (b6 < m) m = b6; if (b7 < m) m = b7;
        u64 o = shflx64(m, 1); if (o < m) m = o;
        o = shflx64(m, 2); if (o < m) m = o;
        if (sc == 0) key128L[r] = m;
      }
      __syncthreads();
      // ---------- derive idx + halt mask (identical in every owner) ----------
      if (tid < 128) {
        u64 key = key128L[tid];
        idxL[tid] = (unsigned)key;
        float d2 = unpackd2(key);
        bool act_b = ((actMbuf[pc][tid >> 6] >> (tid & 63)) & 1ull) != 0ull;
        bool stop = (1.25f * 0.0078125f * d2) < hbias;
        u64 ball = __ballot(act_b && !stop);
        if (ln == 0) actN[tid >> 6] = ball;
      }
      __syncthreads();
      const bool anyAct = (actN[0] | actN[1]) != 0ull;
      if (tid < 2) actMbuf[pc ^ 1u][tid] = actN[tid];
      const bool mf = ((actMbuf[pc][blk >> 6] >> (blk & 63)) & 1ull) != 0ull;
      const unsigned ii = idxL[blk];
      // ---------- z_q fetch + exact vq_loss ----------
      if (tid < 128) {
        float zq = vqe[((size_t)ii << 7) + tid];
        zqL[tid] = zq;
        float df = zq - zfmL[tid];
        float sm = wredsum(df * df);
        if (ln == 0) vqpL[wv] = sm;
      }
      __syncthreads();
      // ---------- tail: entropy (waves 0-1) || candidate (wave 2) ----------
      if (tid < 128) {
        unsigned my = idxL[tid];
        int c = 0;
#pragma unroll
        for (int j4 = 0; j4 < 32; ++j4) {
          uint4 q = *(const uint4*)&idxL[j4 * 4];
          c += (q.x == my) + (q.y == my) + (q.z == my) + (q.w == my);
        }
        float term = -0.0078125f * logf((float)c * 0.0078125f + 1e-10f);
        term = wredsum(term);
        if (ln == 0) entpL[wv] = term;
      } else if (tid < 192) {
        const int d = tid - 128;
        float gate = scalL[0], g0 = scalL[3], g1 = scalL[4], g2 = scalL[5];
        float cr = zfmL[d], ci = zfmL[64 + d];
        float ur = fmaf(g0, qkL[4][d] * gate, fmaf(g1, mrL[d], g2 * zqL[d]));
        float ui = fmaf(g0, qkL[5][d] * gate, fmaf(g1, miL[d], g2 * zqL[64 + d]));
        float cdr = fmaf(0.4f, ur, 0.6f * cr);
        float cdi = fmaf(0.4f, ui, 0.6f * ci);
        float ang = atan2f(cdi, cdr);
        float df = fabsf(ang - pangL[d]);
        df = fminf(df, TWO_PI_F - df);
        pangL[d] = ang;
        float dm = wredsum(df) * 0.015625f;
        if (mf) { gwrowL[d] = cdr; gwrowL[64 + d] = cdi; }
        if (d == 0) dmeanS = dm;
      }
      __syncthreads();
      if (tid == 0) {
        float aold = mf ? 1.0f : 0.0f;
        float vql = 1.25f * (vqpL[0] + vqpL[1]) * 0.0078125f;
        accL[3] += aold * dmeanS;
        accL[2] += aold * 0.01f;
        if (mf) {
          accL[0] = vql;
          accL[1] = entpL[0] + entpL[1];
          dout[(size_t)LOGN + 4 + (size_t)blk * TT + t] = (float)ii;
        }
      }
      __syncthreads();
      k++;
      if (!anyAct) break;
    } // it
  } // t

  // epilogue: final gw out + stats flush + sentinel release for servers
  if (tid < 128) outh[((size_t)blk * TT + (TT - 1)) * 128 + tid] = gwrowL[tid];
  if (tid < 4) rst[blk * 4 + tid] = totL[tid] + accL[tid];
  __syncthreads();
  if (tid == 0) {
    unsigned a = rmw_inc(&ctr[C_AGRP(blk >> 5)]);
    if ((a & 31u) == 31u) {
      unsigned b = rmw_inc(&ctr[C_AMID]);
      if ((b & 3u) == 3u) {
#pragma unroll
        for (int g = 0; g < 4; ++g) st_coh32(&ctr[C_AREL(g)], SENT);
      }
    }
  }
}

__global__ __launch_bounds__(256) void sacrsn_dec(
    const float* __restrict__ dW, const float* __restrict__ dbv,
    float* __restrict__ dout, const char* __restrict__ ws)
{
  const float* outh = (const float*)(ws + OFF_OUTH);
  const float* rst = (const float*)(ws + OFF_RST);
  __shared__ float As[4096];
  __shared__ float Bs[4096];
  const int tid = threadIdx.x;
  const int bx = blockIdx.x & 127;
  const int by = blockIdx.x >> 7;
  const int n0 = bx << 6, m0 = by << 6;
  if (blockIdx.x == 0 && tid < 4) {
    float s = 0.0f;
    for (int r = 0; r < 128; ++r) s += rst[r * 4 + tid];
    dout[(size_t)LOGN + tid] = s * (1.0f / 4096.0f);
  }
  const int ty = tid >> 4, tx = tid & 15;
  float acc[4][4];
#pragma unroll
  for (int i = 0; i < 4; ++i)
#pragma unroll
    for (int j = 0; j < 4; ++j) acc[i][j] = 0.0f;
  for (int kh = 0; kh < 2; ++kh) {
    for (int u = tid; u < 1024; u += 256) {
      const int row = u >> 4, un = u & 15;
      const int sw = ((un ^ row) & 15) << 2;
      *(float4*)&As[(row << 6) + sw] =
          *(const float4*)&outh[((size_t)(m0 + row) << 7) + (kh << 6) + (un << 2)];
      *(float4*)&Bs[(row << 6) + sw] =
          *(const float4*)&dW[((size_t)(n0 + row) << 7) + (kh << 6) + (un << 2)];
    }
    __syncthreads();
#pragma unroll 4
    for (int k4 = 0; k4 < 16; ++k4) {
      float4 a[4], b[4];
#pragma unroll
      for (int ii = 0; ii < 4; ++ii) {
        const int row = (ty << 2) + ii;
        a[ii] = *(const float4*)&As[(row << 6) + (((k4 ^ row) & 15) << 2)];
      }
#pragma unroll
      for (int jj = 0; jj < 4; ++jj) {
        const int row = (tx << 2) + jj;
        b[jj] = *(const float4*)&Bs[(row << 6) + (((k4 ^ row) & 15) << 2)];
      }
#pragma unroll
      for (int ii = 0; ii < 4; ++ii)
#pragma unroll
        for (int jj = 0; jj < 4; ++jj)
          acc[ii][jj] = fmaf(a[ii].x, b[jj].x, fmaf(a[ii].y, b[jj].y,
                        fmaf(a[ii].z, b[jj].z, fmaf(a[ii].w, b[jj].w, acc[ii][jj]))));
    }
    __syncthreads();
  }
#pragma unroll
  for (int ii = 0; ii < 4; ++ii) {
    const int m = m0 + (ty << 2) + ii;
    const int v0 = n0 + (tx << 2);
    float4 o;
    o.x = acc[ii][0] + dbv[v0];
    o.y = acc[ii][1] + dbv[v0 + 1];
    o.z = acc[ii][2] + dbv[v0 + 2];
    o.w = acc[ii][3] + dbv[v0 + 3];
    *(float4*)&dout[((size_t)m << 13) + v0] = o;
  }
}

extern "C" void kernel_launch(void* const* d_in, const int* in_sizes, int n_in,
                              void* d_out, int out_size, void* d_ws, size_t ws_size,
                              hipStream_t stream) {
  (void)in_sizes; (void)n_in; (void)out_size; (void)ws_size;
  const int*   x_seq = (const int*)d_in[0];
  const float* enc = (const float*)d_in[1];
  const float* vq  = (const float*)d_in[2];
  const float* nrg = (const float*)d_in[3];
  const float* nrb = (const float*)d_in[4];
  const float* nig = (const float*)d_in[5];
  const float* nib = (const float*)d_in[6];
  const float* qWr = (const float*)d_in[7];
  const float* qbr = (const float*)d_in[8];
  const float* qWi = (const float*)d_in[9];
  const float* qbi = (const float*)d_in[10];
  const float* gtw = (const float*)d_in[11];
  const float* gtb = (const float*)d_in[12];
  const float* aW  = (const float*)d_in[13];
  const float* ab  = (const float*)d_in[14];
  const float* dW  = (const float*)d_in[15];
  const float* db  = (const float*)d_in[16];
  const float* hb  = (const float*)d_in[17];
  const float* ig  = (const float*)d_in[18];
  char* ws = (char*)d_ws;
  float* out = (float*)d_out;
  hipLaunchKernelGGL(sacrsn_init, dim3(1), dim3(512), 0, stream, ws);
  hipLaunchKernelGGL(sacrsn_main, dim3(NBLK), dim3(NTHR), 0, stream,
                     x_seq, enc, vq, nrg, nrb, nig, nib, qWr, qbr, qWi, qbi,
                     gtw, gtb, aW, ab, hb, ig, out, ws);
  hipLaunchKernelGGL(sacrsn_dec, dim3(8192), dim3(256), 0, stream, dW, db, out, ws);
}